// Round 1
// baseline (518.313 us; speedup 1.0000x reference)
//
#include <hip/hip_runtime.h>
#include <math.h>
#include <stdint.h>

#define LOG2_T 19
#define T_SIZE (1u << LOG2_T)
#define T_MASK (T_SIZE - 1u)
#define N_LEVELS 16
#define N_DENSE 8            // levels 0..7 use dense brick tables (res^3 <= T)
#define PRIME1 2654435761u
#define PRIME2 805459861u

typedef unsigned long long u64;
typedef float f4v __attribute__((ext_vector_type(4)));

struct Params {
    int res[N_LEVELS];
    int brick[N_DENSE];      // B = (res+1)/2 : bricks per axis
    int off[N_DENSE];        // entry offset of each dense level table
    int dense_total;         // total dense entries
};

__device__ __forceinline__ float bf_lo(uint32_t v) { return __uint_as_float(v << 16); }
__device__ __forceinline__ float bf_hi(uint32_t v) { return __uint_as_float(v & 0xFFFF0000u); }

__device__ __forceinline__ uint32_t f32_to_bf16_rne(float f) {
    uint32_t u = __float_as_uint(f);
    u += 0x7FFFu + ((u >> 16) & 1u);
    return u >> 16;
}
__device__ __forceinline__ uint32_t pack2(float2 e) {
    return f32_to_bf16_rne(e.x) | (f32_to_bf16_rne(e.y) << 16);
}

__device__ __forceinline__ void nt_store_f2(float2 v, float2* p) {
    union { float2 f; u64 u; } cv; cv.f = v;
    __builtin_nontemporal_store(cv.u, (u64*)p);
}
__device__ __forceinline__ float2 nt_load_f2(const float2* p) {
    union { float2 f; u64 u; } cv;
    cv.u = __builtin_nontemporal_load((const u64*)p);
    return cv.f;
}

// pair load from a hash table: h0 already masked; ix even guarantees the two
// x-corners are entries (h0, h0^1) = one aligned 8B pair.
__device__ __forceinline__ void pair_load(const uint32_t* __restrict__ t,
                                          uint32_t h0, uint32_t& e0, uint32_t& e1) {
    const uint2 q = *(const uint2*)(t + (h0 & ~1u));
    const bool hi = (h0 & 1u);
    e0 = hi ? q.y : q.x;
    e1 = hi ? q.x : q.y;
}

// ---------- build: fine hash tables (levels 8..15) fp32 -> packed bf16 ----------
__global__ __launch_bounds__(256) void hg_build_fine(
    const float2* __restrict__ emb, uint32_t* __restrict__ tabF)
{
    const int i = blockIdx.x * 256 + threadIdx.x;          // [0, 8*T)
    tabF[i] = pack2(emb[(size_t)N_DENSE * T_SIZE + i]);
}

// ---------- build: dense brick tables (levels 0..7) ----------
__global__ __launch_bounds__(256) void hg_build_dense(
    const float2* __restrict__ emb, uint32_t* __restrict__ tabD, Params P)
{
    const int i = blockIdx.x * 256 + threadIdx.x;
    if (i >= P.dense_total) return;
    int l = 0;
    while (l < N_DENSE - 1 && i >= P.off[l + 1]) ++l;
    const int e = i - P.off[l];
    const int B = P.brick[l], R = P.res[l];
    const int sub = e & 7, br = e >> 3;
    int bx = br % B; int t2 = br / B; int by = t2 % B; int bz = t2 / B;
    int x = bx * 2 + (sub & 1);        if (x > R - 1) x = R - 1;   // pad cells unused
    int y = by * 2 + ((sub >> 1) & 1); if (y > R - 1) y = R - 1;
    int z = bz * 2 + (sub >> 2);       if (z > R - 1) z = R - 1;
    const uint32_t h = ((uint32_t)x ^ ((uint32_t)y * PRIME1) ^ ((uint32_t)z * PRIME2)) & T_MASK;
    tabD[i] = pack2(emb[(size_t)l * T_SIZE + h]);
}

// ---------- gather helpers ----------
struct Pt { int ix, iy, iz; float fx, fy, fz; };

__device__ __forceinline__ Pt prep_point(const float* __restrict__ x, int n,
                                         int rl, float rf) {
    Pt p;
    const float sx = x[n * 3 + 0] * rf;
    const float sy = x[n * 3 + 1] * rf;
    const float sz = x[n * 3 + 2] * rf;
    int ix = (int)sx; ix = ix < 0 ? 0 : (ix > rl - 2 ? rl - 2 : ix);
    int iy = (int)sy; iy = iy < 0 ? 0 : (iy > rl - 2 ? rl - 2 : iy);
    int iz = (int)sz; iz = iz < 0 ? 0 : (iz > rl - 2 ? rl - 2 : iz);
    p.ix = ix; p.iy = iy; p.iz = iz;
    p.fx = sx - (float)ix; p.fy = sy - (float)iy; p.fz = sz - (float)iz;
    return p;
}

// fine (hash) gather: c[k] for corner k = dx + 2*dy + 4*dz
__device__ __forceinline__ void gather_fine(const uint32_t* __restrict__ t,
                                            const Pt& p, uint32_t c[8]) {
    const uint32_t hx0 = (uint32_t)p.ix;
    const uint32_t hy0 = (uint32_t)p.iy * PRIME1, hy1 = hy0 + PRIME1;
    const uint32_t hz0 = (uint32_t)p.iz * PRIME2, hz1 = hz0 + PRIME2;
    const uint32_t n00 = hy0 ^ hz0, n10 = hy1 ^ hz0, n01 = hy0 ^ hz1, n11 = hy1 ^ hz1;
    if ((p.ix & 1) == 0) {
        pair_load(t, (hx0 ^ n00) & T_MASK, c[0], c[1]);
        pair_load(t, (hx0 ^ n10) & T_MASK, c[2], c[3]);
        pair_load(t, (hx0 ^ n01) & T_MASK, c[4], c[5]);
        pair_load(t, (hx0 ^ n11) & T_MASK, c[6], c[7]);
    } else {
        const uint32_t hx1 = hx0 + 1u;
        c[0] = t[(hx0 ^ n00) & T_MASK]; c[1] = t[(hx1 ^ n00) & T_MASK];
        c[2] = t[(hx0 ^ n10) & T_MASK]; c[3] = t[(hx1 ^ n10) & T_MASK];
        c[4] = t[(hx0 ^ n01) & T_MASK]; c[5] = t[(hx1 ^ n01) & T_MASK];
        c[6] = t[(hx0 ^ n11) & T_MASK]; c[7] = t[(hx1 ^ n11) & T_MASK];
    }
}

// dense (brick) gather. Bricks are 2x2x2 cells: entry = (brick<<3) | (x + 2y + 4z).
__device__ __forceinline__ void gather_dense(const uint32_t* __restrict__ t,
                                             int B, const Pt& p, uint32_t c[8]) {
    const int ix = p.ix, iy = p.iy, iz = p.iz;
    const int bx0 = ix >> 1, sx0 = ix & 1;
    const int by0 = iy >> 1, sy0 = iy & 1, by1 = (iy + 1) >> 1, sy1 = (iy + 1) & 1;
    const int bz0 = iz >> 1, sz0 = iz & 1, bz1 = (iz + 1) >> 1, sz1 = (iz + 1) & 1;
    const int zy00 = (((bz0 * B + by0) * B) << 3) | (sy0 << 1) | (sz0 << 2);
    const int zy10 = (((bz0 * B + by1) * B) << 3) | (sy1 << 1) | (sz0 << 2);
    const int zy01 = (((bz1 * B + by0) * B) << 3) | (sy0 << 1) | (sz1 << 2);
    const int zy11 = (((bz1 * B + by1) * B) << 3) | (sy1 << 1) | (sz1 << 2);
    if (sx0 == 0) {
        if (sy0 == 0) {
            // ix,iy both even: y-corners stay in the same brick and are
            // consecutive subs -> c0..c3 and c4..c7 are two aligned 16B quads.
            const uint4 q0 = *(const uint4*)(t + zy00 + (bx0 << 3));
            const uint4 q1 = *(const uint4*)(t + zy01 + (bx0 << 3));
            c[0] = q0.x; c[1] = q0.y; c[2] = q0.z; c[3] = q0.w;
            c[4] = q1.x; c[5] = q1.y; c[6] = q1.z; c[7] = q1.w;
        } else {
            const uint2 q0 = *(const uint2*)(t + zy00 + (bx0 << 3));
            const uint2 q1 = *(const uint2*)(t + zy10 + (bx0 << 3));
            const uint2 q2 = *(const uint2*)(t + zy01 + (bx0 << 3));
            const uint2 q3 = *(const uint2*)(t + zy11 + (bx0 << 3));
            c[0] = q0.x; c[1] = q0.y; c[2] = q1.x; c[3] = q1.y;
            c[4] = q2.x; c[5] = q2.y; c[6] = q3.x; c[7] = q3.y;
        }
    } else {
        const int bx1 = bx0 + 1;
        c[0] = t[zy00 + (bx0 << 3) + 1]; c[1] = t[zy00 + (bx1 << 3)];
        c[2] = t[zy10 + (bx0 << 3) + 1]; c[3] = t[zy10 + (bx1 << 3)];
        c[4] = t[zy01 + (bx0 << 3) + 1]; c[5] = t[zy01 + (bx1 << 3)];
        c[6] = t[zy11 + (bx0 << 3) + 1]; c[7] = t[zy11 + (bx1 << 3)];
    }
}

__device__ __forceinline__ float2 blend8(const uint32_t c[8], const Pt& p) {
    const float wx0 = 1.0f - p.fx, wx1 = p.fx;
    const float wy0 = 1.0f - p.fy, wy1 = p.fy;
    const float wz0 = 1.0f - p.fz, wz1 = p.fz;
    float w, f0 = 0.0f, f1 = 0.0f;
    w = wx0 * wy0 * wz0; f0 = fmaf(w, bf_lo(c[0]), f0); f1 = fmaf(w, bf_hi(c[0]), f1);
    w = wx1 * wy0 * wz0; f0 = fmaf(w, bf_lo(c[1]), f0); f1 = fmaf(w, bf_hi(c[1]), f1);
    w = wx0 * wy1 * wz0; f0 = fmaf(w, bf_lo(c[2]), f0); f1 = fmaf(w, bf_hi(c[2]), f1);
    w = wx1 * wy1 * wz0; f0 = fmaf(w, bf_lo(c[3]), f0); f1 = fmaf(w, bf_hi(c[3]), f1);
    w = wx0 * wy0 * wz1; f0 = fmaf(w, bf_lo(c[4]), f0); f1 = fmaf(w, bf_hi(c[4]), f1);
    w = wx1 * wy0 * wz1; f0 = fmaf(w, bf_lo(c[5]), f0); f1 = fmaf(w, bf_hi(c[5]), f1);
    w = wx0 * wy1 * wz1; f0 = fmaf(w, bf_lo(c[6]), f0); f1 = fmaf(w, bf_hi(c[6]), f1);
    w = wx1 * wy1 * wz1; f0 = fmaf(w, bf_lo(c[7]), f0); f1 = fmaf(w, bf_hi(c[7]), f1);
    float2 o; o.x = f0; o.y = f1;
    return o;
}

// ---------- phase 1: gather + trilinear blend, level-major output ----------
// 2 points per thread (n, n+256): both points' gathers issue before either
// blend consumes -> ~2x loads in flight per wave (latency-bound kernel).
// blockIdx = chunk*16 + level  =>  blockIdx%8 == level%8 : each XCD's L2 sees
// only levels {k, k+8} (~dense(k) + 2MB fine = ~L2 sized).
__global__ __launch_bounds__(256) void hg_levels(
    const float* __restrict__ x,
    const uint32_t* __restrict__ tabF,   // [8, T] packed bf16x2 (levels 8..15)
    const uint32_t* __restrict__ tabD,   // dense brick tables (levels 0..7)
    float2* __restrict__ feat,           // [16, N]
    int N, Params P)
{
    const int l  = blockIdx.x & 15;
    const int n0 = (blockIdx.x >> 4) * 512 + threadIdx.x;
    if (n0 >= N) return;
    const int n1 = n0 + 256;
    const bool hasB = (n1 < N);
    const int nB = hasB ? n1 : n0;

    const int   rl = P.res[l];
    const float rf = (float)(rl - 1);

    const Pt pA = prep_point(x, n0, rl, rf);
    const Pt pB = prep_point(x, nB, rl, rf);

    uint32_t cA[8], cB[8];
    if (l >= N_DENSE) {
        const uint32_t* __restrict__ t = tabF + (size_t)(l - N_DENSE) * T_SIZE;
        gather_fine(t, pA, cA);
        gather_fine(t, pB, cB);
    } else {
        const uint32_t* __restrict__ t = tabD + P.off[l];
        const int B = P.brick[l];
        gather_dense(t, B, pA, cA);
        gather_dense(t, B, pB, cB);
    }

    nt_store_f2(blend8(cA, pA), &feat[(size_t)l * N + n0]);
    if (hasB)
        nt_store_f2(blend8(cB, pB), &feat[(size_t)l * N + n1]);
}

// ---------- phase 2: LDS-tiled transpose [16,N] -> [N,16] float2 ----------
__global__ __launch_bounds__(256) void hg_transpose(
    const float2* __restrict__ feat, f4v* __restrict__ out, int N)
{
    __shared__ float2 st[N_LEVELS][33];
    const int base = blockIdx.x * 32;
    const int t = threadIdx.x;
#pragma unroll
    for (int i = 0; i < 2; ++i) {
        const int idx = i * 256 + t;       // 0..511
        const int l = idx >> 5, p = idx & 31;
        const int n = base + p;
        st[l][p] = (n < N) ? nt_load_f2(&feat[(size_t)l * N + n]) : make_float2(0.f, 0.f);
    }
    __syncthreads();
    const int p = t >> 3, k = t & 7;
    const int n = base + p;
    if (n < N) {
        const float2 a = st[2 * k][p], b = st[2 * k + 1][p];
        f4v o; o.x = a.x; o.y = a.y; o.z = b.x; o.w = b.y;
        __builtin_nontemporal_store(o, &out[(size_t)n * 8 + k]);
    }
}

// ---------- fallback (round-1 kernel): used only if ws is too small ----------
__global__ __launch_bounds__(256) void hg_fallback(
    const float* __restrict__ x, const float* __restrict__ emb,
    float* __restrict__ out, int N, Params P)
{
    const int gid = blockIdx.x * 256 + threadIdx.x;
    const int n = gid >> 4, l = gid & 15;
    if (n >= N) return;
    const int rl = P.res[l];
    const float rf = (float)(rl - 1);
    float sx = x[n * 3 + 0] * rf, sy = x[n * 3 + 1] * rf, sz = x[n * 3 + 2] * rf;
    int ix = (int)sx; ix = ix < 0 ? 0 : (ix > rl - 2 ? rl - 2 : ix);
    int iy = (int)sy; iy = iy < 0 ? 0 : (iy > rl - 2 ? rl - 2 : iy);
    int iz = (int)sz; iz = iz < 0 ? 0 : (iz > rl - 2 ? rl - 2 : iz);
    const float fx = sx - ix, fy = sy - iy, fz = sz - iz;
    const uint32_t hx0 = (uint32_t)ix, hx1 = hx0 + 1u;
    const uint32_t hy0 = (uint32_t)iy * PRIME1, hy1 = hy0 + PRIME1;
    const uint32_t hz0 = (uint32_t)iz * PRIME2, hz1 = hz0 + PRIME2;
    const float2* tab = (const float2*)emb + (size_t)l * T_SIZE;
    float2 e0 = tab[(hx0 ^ hy0 ^ hz0) & T_MASK], e1 = tab[(hx1 ^ hy0 ^ hz0) & T_MASK];
    float2 e2 = tab[(hx0 ^ hy1 ^ hz0) & T_MASK], e3 = tab[(hx1 ^ hy1 ^ hz0) & T_MASK];
    float2 e4 = tab[(hx0 ^ hy0 ^ hz1) & T_MASK], e5 = tab[(hx1 ^ hy0 ^ hz1) & T_MASK];
    float2 e6 = tab[(hx0 ^ hy1 ^ hz1) & T_MASK], e7 = tab[(hx1 ^ hy1 ^ hz1) & T_MASK];
    const float wx0 = 1.0f - fx, wx1 = fx, wy0 = 1.0f - fy, wy1 = fy, wz0 = 1.0f - fz, wz1 = fz;
    float w, f0 = 0.0f, f1 = 0.0f;
    w = wx0 * wy0 * wz0; f0 = fmaf(w, e0.x, f0); f1 = fmaf(w, e0.y, f1);
    w = wx1 * wy0 * wz0; f0 = fmaf(w, e1.x, f0); f1 = fmaf(w, e1.y, f1);
    w = wx0 * wy1 * wz0; f0 = fmaf(w, e2.x, f0); f1 = fmaf(w, e2.y, f1);
    w = wx1 * wy1 * wz0; f0 = fmaf(w, e3.x, f0); f1 = fmaf(w, e3.y, f1);
    w = wx0 * wy0 * wz1; f0 = fmaf(w, e4.x, f0); f1 = fmaf(w, e4.y, f1);
    w = wx1 * wy0 * wz1; f0 = fmaf(w, e5.x, f0); f1 = fmaf(w, e5.y, f1);
    w = wx0 * wy1 * wz1; f0 = fmaf(w, e6.x, f0); f1 = fmaf(w, e6.y, f1);
    w = wx1 * wy1 * wz1; f0 = fmaf(w, e7.x, f0); f1 = fmaf(w, e7.y, f1);
    float2 o; o.x = f0; o.y = f1;
    ((float2*)out)[(size_t)n * N_LEVELS + l] = o;
}

extern "C" void kernel_launch(void* const* d_in, const int* in_sizes, int n_in,
                              void* d_out, int out_size, void* d_ws, size_t ws_size,
                              hipStream_t stream) {
    const float* x   = (const float*)d_in[0];
    const float* emb = (const float*)d_in[1];
    const int N = in_sizes[0] / 3;

    // CPython-identical level resolutions (truncation-sensitive: 16*b^3 == 32)
    Params P;
    const double b = exp((log(512.0) - log(16.0)) / 15.0);
    for (int i = 0; i < N_LEVELS; ++i)
        P.res[i] = (int)(16.0 * pow(b, (double)i));
    int acc = 0;
    for (int i = 0; i < N_DENSE; ++i) {
        P.brick[i] = (P.res[i] + 1) >> 1;
        P.off[i] = acc;
        acc += P.brick[i] * P.brick[i] * P.brick[i] * 8;
    }
    P.dense_total = acc;

    const size_t fine_bytes  = (size_t)N_DENSE * T_SIZE * sizeof(uint32_t);      // 16 MB
    const size_t dense_bytes = ((size_t)acc * sizeof(uint32_t) + 255) & ~255ull; // ~4.2 MB
    const size_t feat_bytes  = (size_t)N_LEVELS * N * sizeof(float2);            // 128 MB

    if (ws_size >= fine_bytes + dense_bytes + feat_bytes) {
        uint32_t* tabF = (uint32_t*)d_ws;
        uint32_t* tabD = (uint32_t*)((char*)d_ws + fine_bytes);
        float2*   feat = (float2*)((char*)d_ws + fine_bytes + dense_bytes);

        hipLaunchKernelGGL(hg_build_fine, dim3(N_DENSE * T_SIZE / 256), dim3(256), 0, stream,
                           (const float2*)emb, tabF);
        hipLaunchKernelGGL(hg_build_dense, dim3((P.dense_total + 255) / 256), dim3(256), 0, stream,
                           (const float2*)emb, tabD, P);

        const int chunks = (N + 511) / 512;
        hipLaunchKernelGGL(hg_levels, dim3(chunks * N_LEVELS), dim3(256), 0, stream,
                           x, tabF, tabD, feat, N, P);

        hipLaunchKernelGGL(hg_transpose, dim3((N + 31) / 32), dim3(256), 0, stream,
                           feat, (f4v*)d_out, N);
    } else {
        hipLaunchKernelGGL(hg_fallback, dim3((N * 16 + 255) / 256), dim3(256), 0, stream,
                           x, emb, (float*)d_out, N, P);
    }
}